// Round 6
// baseline (632.298 us; speedup 1.0000x reference)
//
#include <hip/hip_runtime.h>

#define BN     64
#define KCLS   3
#define PPIX   147456
#define NB1    4096
#define NBINS  2048              // resolver bins (8 KB cnt + 8 KB sum)
#define BPR    72                // stream blocks per row
#define F4BLK  512               // float4 groups per block -> 2048 px
#define CAP    32768             // candidate cap per row (expected ~15-20K)
#define NRUNS  4
#define RUNF4  512               // 2048 px per run
#define NSAMP  8192              // sampled px per row
#define MARGIN 520.0f            // ~16 sigma in sampled-rank units

// ---------------- workspace layout (bytes) ----------------
static const size_t OFF_CAND = 0;                                  // BN*CAP*4 = 8 MB
static const size_t OFF_LO   = OFF_CAND + (size_t)BN * CAP * 4;    // u32[64]
static const size_t OFF_HI   = OFF_LO + 256;                       // u32[64]
static const size_t OFF_CCNT = OFF_HI + 256;                       // int[64]
static const size_t OFF_CHI  = OFF_CCNT + 256;                     // u32[64]
static const size_t OFF_DONE = OFF_CHI + 256;                      // u32[64]
static const size_t OFF_SS   = OFF_DONE + 256;                     // double[64]
static const size_t OFF_ACC  = OFF_SS + 512;                       // double
static const size_t OFF_D2   = OFF_ACC + 8;                        // u32

__device__ __forceinline__ unsigned topk_count(const int* sp_ptr) {
    double sp = (double)sp_ptr[0];
    if (sp > 1.0) sp = 1.0;
    return (unsigned)(sp * 0.15 * (double)PPIX + (1.0 - sp) * (double)PPIX);
}

__device__ __forceinline__ float sel_nll(int t, float a, float b, float c) {
    float lp = (t == 0) ? a : ((t == 1) ? b : ((t == 2) ? c : 0.0f));
    return fmaxf(-lp, 0.0f);   // nll >= 0; kill -0.0
}

// ---------------- kernel 1: sampled bracket + state zeroing -----------------
__global__ __launch_bounds__(256) void k_sample(
    const float* __restrict__ in, const int* __restrict__ tgt, const int* __restrict__ sp,
    unsigned* __restrict__ st_lo, unsigned* __restrict__ st_hi,
    int* __restrict__ ccnt, unsigned* __restrict__ chi, unsigned* __restrict__ done,
    double* __restrict__ st_S, double* __restrict__ accum, unsigned* __restrict__ done2)
{
    __shared__ unsigned hist[NB1];
    __shared__ unsigned csum[256];
    __shared__ int s_bL, s_bH;
    const int tid = threadIdx.x;
    const int row = blockIdx.x;

    for (int i = tid; i < NB1; i += 256) hist[i] = 0u;
    if (tid == 0) { s_bL = 0; s_bH = NB1 - 1; }
    __syncthreads();

    const float4* p0 = (const float4*)(in + (size_t)row * KCLS * PPIX);
    const float4* p1 = p0 + PPIX / 4;
    const float4* p2 = p1 + PPIX / 4;
    const int4*   t4 = (const int4*)(tgt + (size_t)row * PPIX);

    #pragma unroll
    for (int r = 0; r < NRUNS; ++r) {
        #pragma unroll
        for (int jj = 0; jj < RUNF4 / 256; ++jj) {
            const int g = r * (PPIX / 4 / NRUNS) + jj * 256 + tid;
            const int4   t = t4[g];
            const float4 a = p0[g];
            const float4 b = p1[g];
            const float4 c = p2[g];
            float v[4];
            v[0] = sel_nll(t.x, a.x, b.x, c.x);
            v[1] = sel_nll(t.y, a.y, b.y, c.y);
            v[2] = sel_nll(t.z, a.z, b.z, c.z);
            v[3] = sel_nll(t.w, a.w, b.w, c.w);
            #pragma unroll
            for (int q = 0; q < 4; ++q) atomicAdd(&hist[__float_as_uint(v[q]) >> 19], 1u);
        }
    }
    __syncthreads();

    unsigned cl[16]; unsigned cacc = 0;
    const int b0 = tid * 16;
    #pragma unroll
    for (int i = 0; i < 16; ++i) {
        cl[i] = hist[NB1 - 1 - (b0 + i)];
        cacc += cl[i];
    }
    csum[tid] = cacc;
    __syncthreads();
    for (int off = 1; off < 256; off <<= 1) {
        unsigned t2 = (tid >= off) ? csum[tid - off] : 0u;
        __syncthreads();
        csum[tid] += t2;
        __syncthreads();
    }

    const unsigned k = topk_count(sp);
    const float ks = (float)k * ((float)NSAMP / (float)PPIX);
    const float tH = ks - MARGIN;
    const float tL = ks + MARGIN;
    unsigned cum = tid ? csum[tid - 1] : 0u;
    #pragma unroll
    for (int i = 0; i < 16; ++i) {
        const unsigned cb = cl[i];
        const float fc = (float)cum, fe = (float)(cum + cb);
        if (fc < tH && fe >= tH) s_bH = NB1 - 1 - (b0 + i);
        if (fc < tL && fe >= tL) s_bL = NB1 - 1 - (b0 + i);
        cum += cb;
    }
    __syncthreads();
    if (tid == 0) {
        st_lo[row] = ((unsigned)s_bL) << 19;
        st_hi[row] = ((unsigned)s_bH + 1u) << 19;   // bH=4095 -> 0x80000000 (nothing above)
        ccnt[row]  = 0;
        chi[row]   = 0u;
        done[row]  = 0u;
        st_S[row]  = 0.0;
        if (row == 0) { accum[0] = 0.0; done2[0] = 0u; }
    }
}

// ---------------- kernel 2: stream + last-block-per-row resolve + out -------
__global__ __launch_bounds__(256) void k_stream(
    const float* __restrict__ in, const int* __restrict__ tgt, const int* __restrict__ sp,
    const unsigned* __restrict__ st_lo, const unsigned* __restrict__ st_hi,
    float* __restrict__ cand, int* __restrict__ ccnt, unsigned* __restrict__ chi,
    unsigned* __restrict__ done, double* __restrict__ st_S,
    double* __restrict__ accum, unsigned* __restrict__ done2, float* __restrict__ out)
{
    __shared__ unsigned hcnt[NBINS];   // stream phase: aliased as float stage[2048]
    __shared__ float    hsum[NBINS];
    __shared__ double   dred[256];
    __shared__ unsigned cred[256];
    __shared__ int  lcnt, gbase, s_resolver, s_t, s_r;
    __shared__ double s_tail;

    const int tid = threadIdx.x;
    const int row   = blockIdx.x / BPR;
    const int chunk = blockIdx.x % BPR;
    float* stage = (float*)hcnt;       // 2048 floats, exactly one block's pixels

    if (tid == 0) lcnt = 0;
    __syncthreads();

    const unsigned lo = st_lo[row];
    const unsigned hi = st_hi[row];
    const float4* p0 = (const float4*)(in + (size_t)row * KCLS * PPIX);
    const float4* p1 = p0 + PPIX / 4;
    const float4* p2 = p1 + PPIX / 4;
    const int4*   t4 = (const int4*)(tgt + (size_t)row * PPIX);
    const int base = chunk * F4BLK;

    float facc = 0.0f; unsigned cabove = 0;
    #pragma unroll
    for (int j = 0; j < F4BLK / 256; ++j) {
        const int idx = base + j * 256 + tid;
        const int4   t = t4[idx];
        const float4 a = p0[idx];
        const float4 b = p1[idx];
        const float4 cc = p2[idx];
        float v[4];
        v[0] = sel_nll(t.x, a.x, b.x, cc.x);
        v[1] = sel_nll(t.y, a.y, b.y, cc.y);
        v[2] = sel_nll(t.z, a.z, b.z, cc.z);
        v[3] = sel_nll(t.w, a.w, b.w, cc.w);
        #pragma unroll
        for (int q = 0; q < 4; ++q) {
            const unsigned u = __float_as_uint(v[q]);
            if (u >= hi) {
                facc += v[q]; ++cabove;
            } else if (u >= lo) {
                const int s = atomicAdd(&lcnt, 1);
                stage[s] = v[q];
            }
        }
    }
    dred[tid] = (double)facc;
    cred[tid] = cabove;
    __syncthreads();
    for (int s = 128; s > 0; s >>= 1) {
        if (tid < s) { dred[tid] += dred[tid + s]; cred[tid] += cred[tid + s]; }
        __syncthreads();
    }
    if (tid == 0) {
        atomicAdd(&st_S[row], dred[0]);
        if (cred[0]) atomicAdd(&chi[row], cred[0]);
        gbase = atomicAdd(&ccnt[row], lcnt);
    }
    __syncthreads();
    {
        const int nst = lcnt, gb = gbase;
        float* cr = cand + (size_t)row * CAP;
        for (int i = tid; i < nst; i += 256) {
            const int pos = gb + i;
            if (pos < CAP) cr[pos] = stage[i];
        }
    }
    __syncthreads();
    if (tid == 0) {
        __threadfence();
        const unsigned old = atomicAdd(&done[row], 1u);
        s_resolver = (old == BPR - 1) ? 1 : 0;
    }
    __syncthreads();
    if (!s_resolver) return;

    // ================= resolver: this block is last of its row =================
    __threadfence();
    int n = ccnt[row]; if (n > CAP) n = CAP;
    const float* cv = cand + (size_t)row * CAP;
    const unsigned kk = topk_count(sp);
    long rr = (long)kk - (long)chi[row];
    if (rr < 1) rr = 1;
    if (rr > n) rr = n;
    unsigned clo = lo, cbhi = hi;
    if (tid == 0) s_tail = 0.0;
    __syncthreads();

    for (;;) {
        const unsigned width = cbhi - clo;
        const bool exact = (width <= (unsigned)NBINS);
        int s2 = 0;
        if (!exact) {
            const unsigned w1 = width - 1u;
            const int m = 32 - __clz((int)w1);   // w1 < 2^m
            s2 = m - 11;                          // (w1>>s2) < 2048
        }
        for (int i = tid; i < NBINS; i += 256) { hcnt[i] = 0u; hsum[i] = 0.0f; }
        __syncthreads();

        const int n4 = n >> 2;
        const float4* cv4 = (const float4*)cv;
        for (int i = tid; i < n4; i += 256) {
            const float4 f = cv4[i];
            const float vv[4] = {f.x, f.y, f.z, f.w};
            #pragma unroll
            for (int q = 0; q < 4; ++q) {
                const unsigned u = __float_as_uint(vv[q]);
                if (u >= clo && u < cbhi) {
                    const unsigned key = (u - clo) >> s2;
                    atomicAdd(&hcnt[key], 1u);
                    if (!exact) atomicAdd(&hsum[key], vv[q]);
                }
            }
        }
        for (int i = (n4 << 2) + tid; i < n; i += 256) {
            const float v = cv[i];
            const unsigned u = __float_as_uint(v);
            if (u >= clo && u < cbhi) {
                const unsigned key = (u - clo) >> s2;
                atomicAdd(&hcnt[key], 1u);
                if (!exact) atomicAdd(&hsum[key], v);
            }
        }
        __syncthreads();

        // descending scan, 8 bins/thread
        unsigned cl[8]; unsigned cacc = 0;
        const int b0 = tid * 8;
        #pragma unroll
        for (int i = 0; i < 8; ++i) { cl[i] = hcnt[NBINS - 1 - (b0 + i)]; cacc += cl[i]; }
        cred[tid] = cacc;
        __syncthreads();
        for (int off = 1; off < 256; off <<= 1) {
            unsigned t2 = (tid >= off) ? cred[tid - off] : 0u;
            __syncthreads();
            cred[tid] += t2;
            __syncthreads();
        }
        long cum = tid ? (long)cred[tid - 1] : 0;
        #pragma unroll
        for (int i = 0; i < 8; ++i) {
            const long cb = (long)cl[i];
            if (cum < rr && cum + cb >= rr) {     // exactly one (thread,i)
                s_t = NBINS - 1 - (b0 + i);
                s_r = (int)(rr - cum);
            }
            cum += cb;
        }
        __syncthreads();
        const int t = s_t;

        double part = 0.0;
        if (exact) {
            #pragma unroll
            for (int i = 0; i < 8; ++i) {
                const int bin = NBINS - 1 - (b0 + i);
                if (bin > t && cl[i])
                    part += (double)cl[i] * (double)__uint_as_float(clo + (unsigned)bin);
            }
        } else {
            #pragma unroll
            for (int i = 0; i < 8; ++i) {
                const int bin = NBINS - 1 - (b0 + i);
                if (bin > t) part += (double)hsum[bin];
            }
        }
        dred[tid] = part;
        __syncthreads();
        for (int s = 128; s > 0; s >>= 1) {
            if (tid < s) dred[tid] += dred[tid + s];
            __syncthreads();
        }
        if (tid == 0) s_tail += dred[0];
        rr = s_r;
        if (exact) {
            if (tid == 0) s_tail += (double)s_r * (double)__uint_as_float(clo + (unsigned)t);
            break;
        }
        const unsigned nlo = clo + ((unsigned)t << s2);
        unsigned nhi = nlo + (1u << s2);
        if (nhi > cbhi) nhi = cbhi;
        clo = nlo; cbhi = nhi;
        __syncthreads();
    }
    __syncthreads();

    if (tid == 0) {
        const double total = st_S[row] + s_tail;
        atomicAdd(accum, total);
        __threadfence();
        const unsigned o2 = atomicAdd(done2, 1u);
        if (o2 == BN - 1) {
            __threadfence();
            const double a = atomicAdd(accum, 0.0);   // atomic read-back
            out[0] = (float)(a / ((double)BN * (double)kk));
        }
    }
}

extern "C" void kernel_launch(void* const* d_in, const int* in_sizes, int n_in,
                              void* d_out, int out_size, void* d_ws, size_t ws_size,
                              hipStream_t stream)
{
    const float* in  = (const float*)d_in[0];
    const int*   tgt = (const int*)d_in[1];
    const int*   sp  = (const int*)d_in[2];

    char* ws = (char*)d_ws;
    float*    cand  = (float*)(ws + OFF_CAND);
    unsigned* st_lo = (unsigned*)(ws + OFF_LO);
    unsigned* st_hi = (unsigned*)(ws + OFF_HI);
    int*      ccnt  = (int*)(ws + OFF_CCNT);
    unsigned* chi   = (unsigned*)(ws + OFF_CHI);
    unsigned* done  = (unsigned*)(ws + OFF_DONE);
    double*   st_S  = (double*)(ws + OFF_SS);
    double*   accum = (double*)(ws + OFF_ACC);
    unsigned* done2 = (unsigned*)(ws + OFF_D2);

    k_sample<<<BN, 256, 0, stream>>>(in, tgt, sp, st_lo, st_hi, ccnt, chi, done,
                                     st_S, accum, done2);
    k_stream<<<BN * BPR, 256, 0, stream>>>(in, tgt, sp, st_lo, st_hi, cand, ccnt, chi,
                                           done, st_S, accum, done2, (float*)d_out);
}

// Round 7
// 380.025 us; speedup vs baseline: 1.6638x; 1.6638x over previous
//
#include <hip/hip_runtime.h>

#define BN     64
#define KCLS   3
#define PPIX   147456
#define NB1    4096
#define NBR    2048              // resolver bins
#define BPR    72                // stream blocks per row
#define F4BLK  512               // float4 groups per block -> 2048 px
#define CAP    32768             // candidate cap per row (expected ~9.5K)
#define NRUNS  4
#define RUNF4  512               // 2048 px per run
#define NSAMP  8192              // sampled px per row
#define MARGIN 264.0f            // ~8 sigma in sampled-rank units

// ---------------- workspace layout (bytes) ----------------
static const size_t OFF_CAND = 0;                                  // BN*CAP*4 = 8 MB
static const size_t OFF_LO   = OFF_CAND + (size_t)BN * CAP * 4;    // u32[64]
static const size_t OFF_HI   = OFF_LO + 256;                       // u32[64]
static const size_t OFF_CCNT = OFF_HI + 256;                       // int[64]
static const size_t OFF_CHI  = OFF_CCNT + 256;                     // u32[64]
static const size_t OFF_SS   = OFF_CHI + 256;                      // double[64]
static const size_t OFF_ACC  = OFF_SS + 512;                       // double
static const size_t OFF_D2   = OFF_ACC + 8;                        // u32

__device__ __forceinline__ unsigned topk_count(const int* sp_ptr) {
    double sp = (double)sp_ptr[0];
    if (sp > 1.0) sp = 1.0;
    return (unsigned)(sp * 0.15 * (double)PPIX + (1.0 - sp) * (double)PPIX);
}

__device__ __forceinline__ float sel_nll(int t, float a, float b, float c) {
    float lp = (t == 0) ? a : ((t == 1) ? b : ((t == 2) ? c : 0.0f));
    return fmaxf(-lp, 0.0f);   // nll >= 0; kill -0.0
}

// ---------------- kernel 1: sampled bracket + state zeroing -----------------
__global__ __launch_bounds__(256) void k_sample(
    const float* __restrict__ in, const int* __restrict__ tgt, const int* __restrict__ sp,
    unsigned* __restrict__ st_lo, unsigned* __restrict__ st_hi,
    int* __restrict__ ccnt, unsigned* __restrict__ chi,
    double* __restrict__ st_S, double* __restrict__ accum, unsigned* __restrict__ done2)
{
    __shared__ unsigned hist[NB1];
    __shared__ unsigned csum[256];
    __shared__ int s_bL, s_bH;
    const int tid = threadIdx.x;
    const int row = blockIdx.x;

    for (int i = tid; i < NB1; i += 256) hist[i] = 0u;
    if (tid == 0) { s_bL = 0; s_bH = NB1 - 1; }
    __syncthreads();

    const float4* p0 = (const float4*)(in + (size_t)row * KCLS * PPIX);
    const float4* p1 = p0 + PPIX / 4;
    const float4* p2 = p1 + PPIX / 4;
    const int4*   t4 = (const int4*)(tgt + (size_t)row * PPIX);

    #pragma unroll
    for (int r = 0; r < NRUNS; ++r) {
        #pragma unroll
        for (int jj = 0; jj < RUNF4 / 256; ++jj) {
            const int g = r * (PPIX / 4 / NRUNS) + jj * 256 + tid;
            const int4   t = t4[g];
            const float4 a = p0[g];
            const float4 b = p1[g];
            const float4 c = p2[g];
            float v[4];
            v[0] = sel_nll(t.x, a.x, b.x, c.x);
            v[1] = sel_nll(t.y, a.y, b.y, c.y);
            v[2] = sel_nll(t.z, a.z, b.z, c.z);
            v[3] = sel_nll(t.w, a.w, b.w, c.w);
            #pragma unroll
            for (int q = 0; q < 4; ++q) atomicAdd(&hist[__float_as_uint(v[q]) >> 19], 1u);
        }
    }
    __syncthreads();

    unsigned cl[16]; unsigned cacc = 0;
    const int b0 = tid * 16;
    #pragma unroll
    for (int i = 0; i < 16; ++i) {
        cl[i] = hist[NB1 - 1 - (b0 + i)];
        cacc += cl[i];
    }
    csum[tid] = cacc;
    __syncthreads();
    for (int off = 1; off < 256; off <<= 1) {
        unsigned t2 = (tid >= off) ? csum[tid - off] : 0u;
        __syncthreads();
        csum[tid] += t2;
        __syncthreads();
    }

    const unsigned k = topk_count(sp);
    const float ks = (float)k * ((float)NSAMP / (float)PPIX);
    const float tH = ks - MARGIN;
    const float tL = ks + MARGIN;
    unsigned cum = tid ? csum[tid - 1] : 0u;
    #pragma unroll
    for (int i = 0; i < 16; ++i) {
        const unsigned cb = cl[i];
        const float fc = (float)cum, fe = (float)(cum + cb);
        if (fc < tH && fe >= tH) s_bH = NB1 - 1 - (b0 + i);
        if (fc < tL && fe >= tL) s_bL = NB1 - 1 - (b0 + i);
        cum += cb;
    }
    __syncthreads();
    if (tid == 0) {
        st_lo[row] = ((unsigned)s_bL) << 19;
        st_hi[row] = ((unsigned)s_bH + 1u) << 19;   // bH=4095 -> 0x80000000 (nothing above)
        ccnt[row]  = 0;
        chi[row]   = 0u;
        st_S[row]  = 0.0;
        if (row == 0) { accum[0] = 0.0; done2[0] = 0u; }
    }
}

// ---------------- kernel 2: stream, ballot-compact, register sums -----------
__global__ __launch_bounds__(256) void k_stream(
    const float* __restrict__ in, const int* __restrict__ tgt,
    const unsigned* __restrict__ st_lo, const unsigned* __restrict__ st_hi,
    float* __restrict__ cand, int* __restrict__ ccnt, unsigned* __restrict__ chi,
    double* __restrict__ st_S)
{
    __shared__ float    stage[4][512];   // per-wave staging (max 8 px/lane * 64)
    __shared__ double   dred[256];
    __shared__ unsigned cred[256];

    const int tid  = threadIdx.x;
    const int lane = tid & 63;
    const int wv   = tid >> 6;
    const int row   = blockIdx.x / BPR;
    const int chunk = blockIdx.x % BPR;

    const unsigned lo = st_lo[row];
    const unsigned hi = st_hi[row];
    const float4* p0 = (const float4*)(in + (size_t)row * KCLS * PPIX);
    const float4* p1 = p0 + PPIX / 4;
    const float4* p2 = p1 + PPIX / 4;
    const int4*   t4 = (const int4*)(tgt + (size_t)row * PPIX);
    const int base = chunk * F4BLK;
    const unsigned long long lmask = (1ull << lane) - 1ull;

    float facc = 0.0f; unsigned cabove = 0; int wcnt = 0;
    #pragma unroll
    for (int j = 0; j < F4BLK / 256; ++j) {
        const int idx = base + j * 256 + tid;
        const int4   t = t4[idx];
        const float4 a = p0[idx];
        const float4 b = p1[idx];
        const float4 cc = p2[idx];
        float v[4];
        v[0] = sel_nll(t.x, a.x, b.x, cc.x);
        v[1] = sel_nll(t.y, a.y, b.y, cc.y);
        v[2] = sel_nll(t.z, a.z, b.z, cc.z);
        v[3] = sel_nll(t.w, a.w, b.w, cc.w);
        #pragma unroll
        for (int q = 0; q < 4; ++q) {
            const unsigned u = __float_as_uint(v[q]);
            const bool isab = (u >= hi);
            const bool iscd = (!isab) && (u >= lo);
            if (isab) { facc += v[q]; ++cabove; }
            const unsigned long long bal = __ballot(iscd);
            if (iscd) {
                const int off = wcnt + __popcll(bal & lmask);
                stage[wv][off] = v[q];
            }
            wcnt += __popcll(bal);     // uniform across the wave
        }
    }

    // one global atomic per wave, coalesced flush
    int gb = 0;
    if (lane == 0 && wcnt) gb = atomicAdd(&ccnt[row], wcnt);
    gb = __shfl(gb, 0);
    float* cr = cand + (size_t)row * CAP;
    for (int i = lane; i < wcnt; i += 64) {
        const int pos = gb + i;
        if (pos < CAP) cr[pos] = stage[wv][i];
    }

    dred[tid] = (double)facc;
    cred[tid] = cabove;
    __syncthreads();
    for (int s = 128; s > 0; s >>= 1) {
        if (tid < s) { dred[tid] += dred[tid + s]; cred[tid] += cred[tid + s]; }
        __syncthreads();
    }
    if (tid == 0) {
        atomicAdd(&st_S[row], dred[0]);
        if (cred[0]) atomicAdd(&chi[row], cred[0]);
    }
}

// ---------------- kernel 3: count-only narrowing resolve + mean -------------
__global__ __launch_bounds__(256) void k_resolve(
    const float* __restrict__ cand, const int* __restrict__ ccnt,
    const unsigned* __restrict__ chi, const int* __restrict__ sp,
    const unsigned* __restrict__ st_lo, const unsigned* __restrict__ st_hi,
    const double* __restrict__ st_S, double* __restrict__ accum,
    unsigned* __restrict__ done2, float* __restrict__ out)
{
    __shared__ unsigned hc[NBR];
    __shared__ unsigned cred[256];
    __shared__ double   dred[256];
    __shared__ int s_t, s_r;

    const int row = blockIdx.x, tid = threadIdx.x;
    int n = ccnt[row]; if (n > CAP) n = CAP;
    const float* cv = cand + (size_t)row * CAP;
    const unsigned kk = topk_count(sp);
    long rr = (long)kk - (long)chi[row];
    if (rr < 1) rr = 1;
    if (rr > n) rr = n;
    unsigned clo = st_lo[row], cbhi = st_hi[row];

    double tail = 0.0;
    if (n > 0) {
        for (;;) {
            const unsigned width = cbhi - clo;
            const bool exact = (width <= (unsigned)NBR);
            int s2 = 0;
            if (!exact) {
                const unsigned w1 = width - 1u;
                const int m = 32 - __clz((int)w1);   // w1 < 2^m
                s2 = m - 11;                          // (w1>>s2) < 2048
            }
            for (int i = tid; i < NBR; i += 256) hc[i] = 0u;
            __syncthreads();
            for (int i = tid; i < n; i += 256) {
                const unsigned u = __float_as_uint(cv[i]);
                if (u >= clo && u < cbhi) atomicAdd(&hc[(u - clo) >> s2], 1u);
            }
            __syncthreads();

            // descending scan, 8 bins/thread
            unsigned cl[8]; unsigned cacc = 0;
            const int b0 = tid * 8;
            #pragma unroll
            for (int i = 0; i < 8; ++i) { cl[i] = hc[NBR - 1 - (b0 + i)]; cacc += cl[i]; }
            cred[tid] = cacc;
            __syncthreads();
            for (int off = 1; off < 256; off <<= 1) {
                unsigned t2 = (tid >= off) ? cred[tid - off] : 0u;
                __syncthreads();
                cred[tid] += t2;
                __syncthreads();
            }
            long cum = tid ? (long)cred[tid - 1] : 0;
            #pragma unroll
            for (int i = 0; i < 8; ++i) {
                const long cb = (long)cl[i];
                if (cum < rr && cum + cb >= rr) {     // exactly one (thread,i)
                    s_t = NBR - 1 - (b0 + i);
                    s_r = (int)(rr - cum);
                }
                cum += cb;
            }
            __syncthreads();
            if (exact) break;
            const unsigned nlo = clo + ((unsigned)s_t << s2);
            unsigned nhi = nlo + (1u << s2);
            if (nhi > cbhi) nhi = cbhi;
            clo = nlo; cbhi = nhi;
            rr = s_r;
            __syncthreads();
        }
        // t = exact rr-th largest candidate bit pattern; s_r = copies of t needed
        const unsigned tbits = clo + (unsigned)s_t;
        double acc = 0.0;
        for (int i = tid; i < n; i += 256) {
            const float v = cv[i];
            if (__float_as_uint(v) > tbits) acc += (double)v;
        }
        dred[tid] = acc;
        __syncthreads();
        for (int s = 128; s > 0; s >>= 1) {
            if (tid < s) dred[tid] += dred[tid + s];
            __syncthreads();
        }
        if (tid == 0)
            tail = dred[0] + (double)s_r * (double)__uint_as_float(tbits);
    }

    if (tid == 0) {
        atomicAdd(accum, st_S[row] + tail);
        __threadfence();
        const unsigned o2 = atomicAdd(done2, 1u);
        if (o2 == BN - 1) {
            __threadfence();
            const double a = atomicAdd(accum, 0.0);   // coherent read-back
            out[0] = (float)(a / ((double)BN * (double)kk));
        }
    }
}

extern "C" void kernel_launch(void* const* d_in, const int* in_sizes, int n_in,
                              void* d_out, int out_size, void* d_ws, size_t ws_size,
                              hipStream_t stream)
{
    const float* in  = (const float*)d_in[0];
    const int*   tgt = (const int*)d_in[1];
    const int*   sp  = (const int*)d_in[2];

    char* ws = (char*)d_ws;
    float*    cand  = (float*)(ws + OFF_CAND);
    unsigned* st_lo = (unsigned*)(ws + OFF_LO);
    unsigned* st_hi = (unsigned*)(ws + OFF_HI);
    int*      ccnt  = (int*)(ws + OFF_CCNT);
    unsigned* chi   = (unsigned*)(ws + OFF_CHI);
    double*   st_S  = (double*)(ws + OFF_SS);
    double*   accum = (double*)(ws + OFF_ACC);
    unsigned* done2 = (unsigned*)(ws + OFF_D2);

    k_sample <<<BN, 256, 0, stream>>>(in, tgt, sp, st_lo, st_hi, ccnt, chi,
                                      st_S, accum, done2);
    k_stream <<<BN * BPR, 256, 0, stream>>>(in, tgt, st_lo, st_hi, cand, ccnt, chi, st_S);
    k_resolve<<<BN, 256, 0, stream>>>(cand, ccnt, chi, sp, st_lo, st_hi,
                                      st_S, accum, done2, (float*)d_out);
}

// Round 8
// 286.956 us; speedup vs baseline: 2.2035x; 1.3243x over previous
//
#include <hip/hip_runtime.h>

#define BN      64
#define KCLS    3
#define PPIX    147456
#define NB1     4096
#define NBR     2048
#define BPR     36               // blocks per row
#define PXB     4096             // pixels per block
#define PXT     16               // pixels per thread (4 batches of float4)
#define NBLK    (BN * BPR)       // 2304
#define CANDCAP 2048             // per-block candidate slots (expect ~550)

// ---------------- workspace layout (bytes) ----------------
static const size_t OFF_BSUM = 0;                                  // NBLK*8
static const size_t OFF_BCNT = OFF_BSUM + (size_t)NBLK * 8;        // NBLK*4
static const size_t OFF_BCC  = OFF_BCNT + (size_t)NBLK * 4;        // NBLK*4
static const size_t OFF_ACC  = OFF_BCC + (size_t)NBLK * 4;         // double (8-aligned)
static const size_t OFF_D2   = OFF_ACC + 8;                        // u32
static const size_t OFF_CAND = OFF_D2 + 8;                         // NBLK*CANDCAP*4 = 18.9 MB

__device__ __forceinline__ unsigned topk_count(const int* sp_ptr) {
    double sp = (double)sp_ptr[0];
    if (sp > 1.0) sp = 1.0;
    return (unsigned)(sp * 0.15 * (double)PPIX + (1.0 - sp) * (double)PPIX);
}

__device__ __forceinline__ float sel_nll(int t, float a, float b, float c) {
    float lp = (t == 0) ? a : ((t == 1) ? b : ((t == 2) ? c : 0.0f));
    return fmaxf(-lp, 0.0f);   // nll >= 0; kill -0.0
}

// ------------- kernel 1: pipelined stream + self-bracket + compact ----------
__global__ __launch_bounds__(256, 4) void k_stream(
    const float* __restrict__ in, const int* __restrict__ tgt, const int* __restrict__ sp,
    double* __restrict__ bsum, unsigned* __restrict__ bcnt, unsigned* __restrict__ bccnt,
    float* __restrict__ cand, double* __restrict__ accum, unsigned* __restrict__ done2)
{
    __shared__ unsigned hist[NB1];     // 16 KB
    __shared__ unsigned cred[256];
    __shared__ double   dred[256];
    __shared__ int s_bL, s_bH, lcnt;

    const int tid   = threadIdx.x;
    const int row   = blockIdx.x / BPR;
    const int chunk = blockIdx.x % BPR;

    if (blockIdx.x == 0 && tid == 0) { accum[0] = 0.0; done2[0] = 0u; } // consumed only in kernel 2

    for (int i = tid; i < NB1; i += 256) hist[i] = 0u;
    if (tid == 0) { s_bL = 0; s_bH = NB1 - 1; lcnt = 0; }
    __syncthreads();

    const float4* p0 = (const float4*)(in + (size_t)row * KCLS * PPIX);
    const float4* p1 = p0 + PPIX / 4;
    const float4* p2 = p1 + PPIX / 4;
    const int4*   t4 = (const int4*)(tgt + (size_t)row * PPIX);
    const int base = chunk * (PXB / 4);

    // ---- register double-buffered load pipeline: 8 loads in flight ----
    float v[PXT];
    int idx0 = base + tid;
    int4   T0 = t4[idx0];
    float4 A0 = p0[idx0], B0 = p1[idx0], C0 = p2[idx0];
    #pragma unroll
    for (int b = 0; b < 4; ++b) {
        int4 T1; float4 A1, B1, C1;
        if (b < 3) {
            const int ni = base + (b + 1) * 256 + tid;
            T1 = t4[ni]; A1 = p0[ni]; B1 = p1[ni]; C1 = p2[ni];
        }
        v[4*b+0] = sel_nll(T0.x, A0.x, B0.x, C0.x);
        v[4*b+1] = sel_nll(T0.y, A0.y, B0.y, C0.y);
        v[4*b+2] = sel_nll(T0.z, A0.z, B0.z, C0.z);
        v[4*b+3] = sel_nll(T0.w, A0.w, B0.w, C0.w);
        atomicAdd(&hist[__float_as_uint(v[4*b+0]) >> 19], 1u);
        atomicAdd(&hist[__float_as_uint(v[4*b+1]) >> 19], 1u);
        atomicAdd(&hist[__float_as_uint(v[4*b+2]) >> 19], 1u);
        atomicAdd(&hist[__float_as_uint(v[4*b+3]) >> 19], 1u);
        T0 = T1; A0 = A1; B0 = B1; C0 = C1;
    }
    __syncthreads();

    // ---- local descending scan: bracket this block's 4096 values ----
    // rank targets from Binomial(PXB, p): margin 10*sigma + 8
    const unsigned k = topk_count(sp);
    const float p  = (float)k / (float)PPIX;
    const float mu = (float)PXB * p;
    const float sg = sqrtf((float)PXB * p * (1.0f - p));
    const float marg = 10.0f * sg + 8.0f;
    const float tH = mu - marg;            // definite-top rank bound
    const float tL = mu + marg;            // definite-out rank bound

    unsigned cl[16]; unsigned cacc = 0;
    const int b0 = tid * 16;
    #pragma unroll
    for (int i = 0; i < 16; ++i) {
        cl[i] = hist[NB1 - 1 - (b0 + i)];
        cacc += cl[i];
    }
    cred[tid] = cacc;
    __syncthreads();
    for (int off = 1; off < 256; off <<= 1) {
        unsigned t2 = (tid >= off) ? cred[tid - off] : 0u;
        __syncthreads();
        cred[tid] += t2;
        __syncthreads();
    }
    {
        unsigned cum = tid ? cred[tid - 1] : 0u;
        #pragma unroll
        for (int i = 0; i < 16; ++i) {
            const unsigned cb = cl[i];
            const float fc = (float)cum, fe = (float)(cum + cb);
            if (fc < tH && fe >= tH) s_bH = NB1 - 1 - (b0 + i);
            if (fc < tL && fe >= tL) s_bL = NB1 - 1 - (b0 + i);
            cum += cb;
        }
    }
    __syncthreads();

    // ---- classify from registers ----
    const unsigned hi = ((unsigned)s_bH + 1u) << 19;   // u >= hi: definitely in top-k
    const unsigned lo = ((unsigned)s_bL) << 19;        // u in [lo,hi): candidate
    double acc = 0.0; unsigned cab = 0;
    float* cr = cand + (size_t)blockIdx.x * CANDCAP;
    #pragma unroll
    for (int i = 0; i < PXT; ++i) {
        const unsigned u = __float_as_uint(v[i]);
        if (u >= hi) {
            acc += (double)v[i]; ++cab;
        } else if (u >= lo) {
            const int pos = atomicAdd(&lcnt, 1);
            if (pos < CANDCAP) cr[pos] = v[i];
        }
    }
    dred[tid] = acc; cred[tid] = cab;
    __syncthreads();
    for (int s = 128; s > 0; s >>= 1) {
        if (tid < s) { dred[tid] += dred[tid + s]; cred[tid] += cred[tid + s]; }
        __syncthreads();
    }
    if (tid == 0) {
        bsum[blockIdx.x]  = dred[0];
        bcnt[blockIdx.x]  = cred[0];
        bccnt[blockIdx.x] = (unsigned)((lcnt > CANDCAP) ? CANDCAP : lcnt);
    }
}

// ------------- kernel 2: per-row exact resolve + last-finisher mean ---------
__global__ __launch_bounds__(256) void k_resolve(
    const float* __restrict__ cand, const unsigned* __restrict__ bccnt,
    const unsigned* __restrict__ bcnt, const double* __restrict__ bsum,
    const int* __restrict__ sp, double* __restrict__ accum,
    unsigned* __restrict__ done2, float* __restrict__ out)
{
    __shared__ unsigned hc[NBR];
    __shared__ unsigned cred[256];
    __shared__ double   dred[256];
    __shared__ int s_t, s_r;

    const int row = blockIdx.x, tid = threadIdx.x;
    const unsigned k = topk_count(sp);

    // row totals from per-block slots
    {
        double a = 0.0; unsigned c = 0;
        for (int s = tid; s < BPR; s += 256) {
            a += bsum[row * BPR + s];
            c += bcnt[row * BPR + s];
        }
        dred[tid] = a; cred[tid] = c;
        __syncthreads();
        for (int s = 128; s > 0; s >>= 1) {
            if (tid < s) { dred[tid] += dred[tid + s]; cred[tid] += cred[tid + s]; }
            __syncthreads();
        }
    }
    const double S = dred[0];
    const unsigned above = cred[0];
    long rr = (long)k - (long)above;       // margin construction guarantees rr >= 1
    if (rr < 1) rr = 1;
    __syncthreads();

    // count-only bit-range narrowing: [0, 2^31) -> exact in 3 passes
    unsigned clo = 0u, cbhi = 0x80000000u;
    for (;;) {
        const unsigned width = cbhi - clo;
        const bool exact = (width <= (unsigned)NBR);
        int s2 = 0;
        if (!exact) {
            const unsigned w1 = width - 1u;
            const int m = 32 - __clz((int)w1);   // w1 < 2^m
            s2 = m - 11;                          // (w1 >> s2) < 2048
        }
        for (int i = tid; i < NBR; i += 256) hc[i] = 0u;
        __syncthreads();
        for (int seg = 0; seg < BPR; ++seg) {
            const int bi = row * BPR + seg;
            const int sn = (int)bccnt[bi];
            const float* sv = cand + (size_t)bi * CANDCAP;
            for (int i = tid; i < sn; i += 256) {
                const unsigned u = __float_as_uint(sv[i]);
                if (u >= clo && u < cbhi) atomicAdd(&hc[(u - clo) >> s2], 1u);
            }
        }
        __syncthreads();

        unsigned cl[8]; unsigned cacc = 0;
        const int b0 = tid * 8;
        #pragma unroll
        for (int i = 0; i < 8; ++i) { cl[i] = hc[NBR - 1 - (b0 + i)]; cacc += cl[i]; }
        cred[tid] = cacc;
        __syncthreads();
        for (int off = 1; off < 256; off <<= 1) {
            unsigned t2 = (tid >= off) ? cred[tid - off] : 0u;
            __syncthreads();
            cred[tid] += t2;
            __syncthreads();
        }
        long cum = tid ? (long)cred[tid - 1] : 0;
        #pragma unroll
        for (int i = 0; i < 8; ++i) {
            const long cb = (long)cl[i];
            if (cum < rr && cum + cb >= rr) {   // exactly one (thread,i)
                s_t = NBR - 1 - (b0 + i);
                s_r = (int)(rr - cum);
            }
            cum += cb;
        }
        __syncthreads();
        if (exact) break;
        const unsigned nlo = clo + ((unsigned)s_t << s2);
        unsigned nhi = nlo + (1u << s2);
        if (nhi > cbhi) nhi = cbhi;
        clo = nlo; cbhi = nhi;
        rr = s_r;
        __syncthreads();
    }

    // exact threshold bits; sum candidates strictly above + tie copies
    const unsigned tbits = clo + (unsigned)s_t;
    double acc = 0.0;
    for (int seg = 0; seg < BPR; ++seg) {
        const int bi = row * BPR + seg;
        const int sn = (int)bccnt[bi];
        const float* sv = cand + (size_t)bi * CANDCAP;
        for (int i = tid; i < sn; i += 256) {
            const float x = sv[i];
            if (__float_as_uint(x) > tbits) acc += (double)x;
        }
    }
    dred[tid] = acc;
    __syncthreads();
    for (int s = 128; s > 0; s >>= 1) {
        if (tid < s) dred[tid] += dred[tid + s];
        __syncthreads();
    }

    if (tid == 0) {
        const double total = S + dred[0] + (double)s_r * (double)__uint_as_float(tbits);
        atomicAdd(accum, total);
        __threadfence();
        const unsigned o2 = atomicAdd(done2, 1u);
        if (o2 == BN - 1) {
            __threadfence();
            const double a = atomicAdd(accum, 0.0);   // coherent read-back
            out[0] = (float)(a / ((double)BN * (double)k));
        }
    }
}

extern "C" void kernel_launch(void* const* d_in, const int* in_sizes, int n_in,
                              void* d_out, int out_size, void* d_ws, size_t ws_size,
                              hipStream_t stream)
{
    const float* in  = (const float*)d_in[0];
    const int*   tgt = (const int*)d_in[1];
    const int*   sp  = (const int*)d_in[2];

    char* ws = (char*)d_ws;
    double*   bsum  = (double*)(ws + OFF_BSUM);
    unsigned* bcnt  = (unsigned*)(ws + OFF_BCNT);
    unsigned* bccnt = (unsigned*)(ws + OFF_BCC);
    double*   accum = (double*)(ws + OFF_ACC);
    unsigned* done2 = (unsigned*)(ws + OFF_D2);
    float*    cand  = (float*)(ws + OFF_CAND);

    k_stream <<<NBLK, 256, 0, stream>>>(in, tgt, sp, bsum, bcnt, bccnt, cand, accum, done2);
    k_resolve<<<BN, 256, 0, stream>>>(cand, bccnt, bcnt, bsum, sp, accum, done2, (float*)d_out);
}